// Round 4
// baseline (490.996 us; speedup 1.0000x reference)
//
#include <hip/hip_runtime.h>
#include <hip/hip_bf16.h>
#include <math.h>

#define B_   16
#define S_   4096
#define D_   768
#define H_   384
#define NTOK (B_ * S_)
#define KTOP 40
#define NTILES 24          // 384/16 n-tiles
#define KCH    24          // 768/32 k-chunks
#define CHSTRIDE (4 * 64 * 96)   // shorts per chunk in packed B (=24576)

typedef __attribute__((ext_vector_type(8))) short bf16x8;
typedef __attribute__((ext_vector_type(4))) float f32x4;

static __device__ __forceinline__ unsigned short f2bf(float x) {
    // HW RNE convert (compiler emits native cvt; RNE == old software path)
    __hip_bfloat16 h = __float2bfloat16(x);
    unsigned short r;
    __builtin_memcpy(&r, &h, sizeof(r));
    return r;
}
static __device__ __forceinline__ float bf2f(unsigned short h) {
    union { unsigned u; float f; } v; v.u = ((unsigned)h) << 16; return v.f;
}

// ---------------------------------------------------------------------------
// Kernel 0: pack W1 (fp32 [768][384]) into per-lane-contiguous MFMA B layout:
// bp[ ((ch*4 + w)*64 + lane)*96 + tl*16 + hl*8 + j ]   (shorts)
//   w = wave (nt/6), tl = n-tile within wave (nt%6), hl = 0 hi / 1 lo.
// Fragment element j of lane: B[k = ch*32 + (lane>>4)*8 + j][n = nt*16 + (lane&15)]
// A lane's 12 fragments for one (chunk, wave) are 192 contiguous bytes ->
// score kernel loads them with one base address + immediate offsets.
// ---------------------------------------------------------------------------
__global__ __launch_bounds__(64) void pack_w1(const float* __restrict__ W1,
                                              unsigned short* __restrict__ bp)
{
    const int nt   = blockIdx.x;        // 0..23
    const int ch   = blockIdx.y;        // 0..23
    const int lane = threadIdx.x;
    const int w    = nt / 6;
    const int tl   = nt % 6;
    const int n    = nt * 16 + (lane & 15);
    const int k0   = ch * 32 + (lane >> 4) * 8;

    const size_t dst = ((size_t)(ch * 4 + w) * 64 + lane) * 96 + tl * 16;
#pragma unroll
    for (int j = 0; j < 8; ++j) {
        const float v = W1[(size_t)(k0 + j) * H_ + n];
        const unsigned short h = f2bf(v);
        bp[dst + j]     = h;
        bp[dst + 8 + j] = f2bf(v - bf2f(h));
    }
}

// ---------------------------------------------------------------------------
// Kernel 1: fused scores. v5 = v3 structure (best: 205us) + two VALU cuts:
//  - HW bf16 convert in staging (was 4-op software RNE per element)
//  - per-lane-contiguous packed B: 12 loads = 1 base + imm offsets 0..176B,
//    base advances by constant 49152B per chunk (kills 64-bit addr muls)
// Block = 32 tokens x 384 cols (grid 2048), 4 waves; wave w owns n-tiles
// w*6..w*6+5 and 2 m-subtiles. acc 48 VGPR; launch_bounds(256,4) -> 4
// blocks/CU. Per-chunk barrier pair exactly as v3 (v4's pair-staging ring
// regressed; do not touch the schedule). Accumulation order identical.
// ---------------------------------------------------------------------------
__global__ __launch_bounds__(256, 4) void score_kernel(
    const float* __restrict__ features,
    const unsigned short* __restrict__ bp_g,
    const float* __restrict__ b1,
    const float* __restrict__ gamma,
    const float* __restrict__ beta,
    const float* __restrict__ W2,
    const float* __restrict__ b2,
    float* __restrict__ scores)
{
    __shared__ unsigned short Ah[32][40];   // pad 32->40 (16B-aligned rows)
    __shared__ unsigned short Al[32][40];
    __shared__ float red[4][32];
    __shared__ float mu_s[32];
    __shared__ float rs_s[32];

    const int tid  = threadIdx.x;
    const int lane = tid & 63;
    const int w    = tid >> 6;
    const int base = blockIdx.x * 32;
    const int cl   = lane & 15;
    const int p    = lane >> 4;

    f32x4 acc[2][6];
#pragma unroll
    for (int m = 0; m < 2; ++m)
#pragma unroll
        for (int t = 0; t < 6; ++t) acc[m][t] = (f32x4){0.f, 0.f, 0.f, 0.f};

    // staging map: thread covers one float4: row = tid>>3 (0..31), col4 = (tid&7)*4
    const int r0 = tid >> 3, c0 = (tid & 7) * 4;
    const float* arow = features + (size_t)(base + r0) * D_ + c0;

    // per-wave per-lane packed-B base (chunk 0); advances CHSTRIDE per chunk
    const unsigned short* bpw = bp_g + ((size_t)w * 64 + lane) * 96;

    float4 p0 = *(const float4*)(arow);

    for (int c = 0; c < KCH; ++c) {
        if (c) __syncthreads();
        // convert + write staged chunk
        {
            unsigned short h0 = f2bf(p0.x), h1 = f2bf(p0.y), h2 = f2bf(p0.z), h3 = f2bf(p0.w);
            Ah[r0][c0] = h0; Ah[r0][c0+1] = h1; Ah[r0][c0+2] = h2; Ah[r0][c0+3] = h3;
            Al[r0][c0]   = f2bf(p0.x - bf2f(h0));
            Al[r0][c0+1] = f2bf(p0.y - bf2f(h1));
            Al[r0][c0+2] = f2bf(p0.z - bf2f(h2));
            Al[r0][c0+3] = f2bf(p0.w - bf2f(h3));
        }
        // prefetch next chunk (overlaps barrier + MFMA below)
        if (c + 1 < KCH) {
            p0 = *(const float4*)(arow + (c + 1) * 32);
        }
        __syncthreads();

        // A fragments for the 2 m-subtiles
        bf16x8 ahf[2], alf[2];
#pragma unroll
        for (int m = 0; m < 2; ++m) {
            const int row = m * 16 + cl;
            ahf[m] = *(const bf16x8*)&Ah[row][p * 8];
            alf[m] = *(const bf16x8*)&Al[row][p * 8];
        }
        // B fragments: 12 loads off one base with immediate offsets
        const unsigned short* bb = bpw + (size_t)c * CHSTRIDE;
#pragma unroll
        for (int t = 0; t < 6; ++t) {
            const bf16x8 bhf = *(const bf16x8*)(bb + t * 16);
            const bf16x8 blf = *(const bf16x8*)(bb + t * 16 + 8);
#pragma unroll
            for (int m = 0; m < 2; ++m) {
                acc[m][t] = __builtin_amdgcn_mfma_f32_16x16x32_bf16(ahf[m], bhf, acc[m][t], 0, 0, 0);
                acc[m][t] = __builtin_amdgcn_mfma_f32_16x16x32_bf16(ahf[m], blf, acc[m][t], 0, 0, 0);
                acc[m][t] = __builtin_amdgcn_mfma_f32_16x16x32_bf16(alf[m], bhf, acc[m][t], 0, 0, 0);
            }
        }
    }

    // ---- epilogue: per-column constants ----
    float b1v[6], gv[6], bev[6], w2v[6];
#pragma unroll
    for (int t = 0; t < 6; ++t) {
        const int n = (w * 6 + t) * 16 + cl;
        b1v[t] = b1[n]; gv[t] = gamma[n]; bev[t] = beta[n]; w2v[t] = W2[n];
    }
    // h = acc + b1
#pragma unroll
    for (int m = 0; m < 2; ++m)
#pragma unroll
        for (int t = 0; t < 6; ++t)
#pragma unroll
            for (int r = 0; r < 4; ++r) acc[m][t][r] += b1v[t];

    // pass 1: row sums -> mean
#pragma unroll
    for (int m = 0; m < 2; ++m) {
        float sm[4] = {0.f, 0.f, 0.f, 0.f};
#pragma unroll
        for (int t = 0; t < 6; ++t)
#pragma unroll
            for (int r = 0; r < 4; ++r) sm[r] += acc[m][t][r];
#pragma unroll
        for (int r = 0; r < 4; ++r) {
#pragma unroll
            for (int off = 1; off <= 8; off <<= 1) sm[r] += __shfl_xor(sm[r], off, 64);
        }
        if (cl == 0) {
#pragma unroll
            for (int r = 0; r < 4; ++r) red[w][m * 16 + p * 4 + r] = sm[r];
        }
    }
    __syncthreads();
    if (tid < 32) mu_s[tid] = (red[0][tid] + red[1][tid] + red[2][tid] + red[3][tid]) * (1.0f / H_);
    __syncthreads();

    // pass 2: variance (two-pass, matches reference)
#pragma unroll
    for (int m = 0; m < 2; ++m) {
        float mur[4];
#pragma unroll
        for (int r = 0; r < 4; ++r) mur[r] = mu_s[m * 16 + p * 4 + r];
        float sm[4] = {0.f, 0.f, 0.f, 0.f};
#pragma unroll
        for (int t = 0; t < 6; ++t)
#pragma unroll
            for (int r = 0; r < 4; ++r) { const float d = acc[m][t][r] - mur[r]; sm[r] += d * d; }
#pragma unroll
        for (int r = 0; r < 4; ++r) {
#pragma unroll
            for (int off = 1; off <= 8; off <<= 1) sm[r] += __shfl_xor(sm[r], off, 64);
        }
        if (cl == 0) {
#pragma unroll
            for (int r = 0; r < 4; ++r) red[w][m * 16 + p * 4 + r] = sm[r];
        }
    }
    __syncthreads();
    if (tid < 32) rs_s[tid] = rsqrtf((red[0][tid] + red[1][tid] + red[2][tid] + red[3][tid]) * (1.0f / H_) + 1e-5f);
    __syncthreads();

    // pass 3: y = LN*gamma+beta, gelu, dot with W2
#pragma unroll
    for (int m = 0; m < 2; ++m) {
        float mur[4], rsr[4];
#pragma unroll
        for (int r = 0; r < 4; ++r) { mur[r] = mu_s[m * 16 + p * 4 + r]; rsr[r] = rs_s[m * 16 + p * 4 + r]; }
        float sm[4] = {0.f, 0.f, 0.f, 0.f};
#pragma unroll
        for (int t = 0; t < 6; ++t)
#pragma unroll
            for (int r = 0; r < 4; ++r) {
                const float y  = (acc[m][t][r] - mur[r]) * rsr[r] * gv[t] + bev[t];
                const float ge = 0.5f * y * (1.0f + erff(y * 0.70710678118654752f));
                sm[r] = fmaf(ge, w2v[t], sm[r]);
            }
#pragma unroll
        for (int r = 0; r < 4; ++r) {
#pragma unroll
            for (int off = 1; off <= 8; off <<= 1) sm[r] += __shfl_xor(sm[r], off, 64);
        }
        if (cl == 0) {
#pragma unroll
            for (int r = 0; r < 4; ++r) red[w][m * 16 + p * 4 + r] = sm[r];
        }
    }
    __syncthreads();
    if (tid < 32) {
        const float s = red[0][tid] + red[1][tid] + red[2][tid] + red[3][tid] + b2[0];
        scores[base + tid] = 1.0f / (1.0f + expf(-s));
    }
}

// ---------------------------------------------------------------------------
// Kernel 2: per-batch exact top-40 via byte-wise radix select on float bits
// (scores > 0 so uint order == float order). Ties -> lower index.
// Wave-parallel suffix-sum threshold scan (v4). Same semantics as serial.
// ---------------------------------------------------------------------------
__global__ __launch_bounds__(256) void select_kernel(const float* __restrict__ scores,
                                                     int* __restrict__ sel)
{
    __shared__ unsigned int bits_s[S_];     // 16 KB
    __shared__ unsigned int hist[256];
    __shared__ unsigned int suf[256];
    __shared__ unsigned int wtot[4];
    __shared__ int s_byte, s_rem;
    __shared__ unsigned int s_ngt, s_neq;
    __shared__ unsigned int candV[64];
    __shared__ int candI[64];
    __shared__ int eqI[256];

    const int b    = blockIdx.x;
    const int tid  = threadIdx.x;
    const int lane = tid & 63;
    const int w4   = tid >> 6;

    for (int i = tid; i < S_; i += 256)
        bits_s[i] = __float_as_uint(scores[b * S_ + i]);
    if (tid == 0) { s_rem = KTOP; s_ngt = 0u; s_neq = 0u; }

    unsigned int prefix = 0u, mask = 0u;
    for (int pb = 3; pb >= 0; --pb) {
        hist[tid] = 0u;
        __syncthreads();
        for (int i = tid; i < S_; i += 256) {
            const unsigned int u = bits_s[i];
            if ((u & mask) == prefix) atomicAdd(&hist[(u >> (8 * pb)) & 255u], 1u);
        }
        __syncthreads();
        // inclusive suffix sum over 256 bins: segment-local via shuffles
        {
            unsigned int v = hist[tid];
#pragma unroll
            for (int off = 1; off < 64; off <<= 1) {
                const unsigned int y = __shfl_down(v, off, 64);
                if (lane + off < 64) v += y;
            }
            if (lane == 0) wtot[w4] = v;   // segment totals
            __syncthreads();
            unsigned int add = 0u;
#pragma unroll
            for (int j = 0; j < 4; ++j) if (j > w4) add += wtot[j];
            v += add;
            suf[tid] = v;                  // suf[t] = #values with byte >= t (given prefix)
            __syncthreads();
            const int rem = s_rem;
            const unsigned int nxt = (tid < 255) ? suf[tid + 1] : 0u;
            if (suf[tid] >= (unsigned)rem && (tid == 255 || nxt < (unsigned)rem)) {
                s_byte = tid;
                s_rem  = rem - (int)nxt;   // subtract count strictly above byte
            }
        }
        __syncthreads();
        prefix |= ((unsigned int)s_byte) << (8 * pb);
        mask   |= 0xFFu << (8 * pb);
        __syncthreads();
    }
    const unsigned int T = prefix;
    const int need = s_rem;                 // 1..: #ties at T to keep

    for (int i = tid; i < S_; i += 256) {
        const unsigned int u = bits_s[i];
        if (u > T) {
            const unsigned int pos = atomicAdd(&s_ngt, 1u);
            candV[pos] = u; candI[pos] = i;          // n_gt <= 39 guaranteed
        } else if (u == T) {
            const unsigned int pos = atomicAdd(&s_neq, 1u);
            if (pos < 256u) eqI[pos] = i;
        }
    }
    __syncthreads();
    const int ngt = (int)s_ngt;
    const int neq = (int)(s_neq < 256u ? s_neq : 256u);
    // keep the `need` smallest indices among ties
    for (int j = tid; j < neq; j += 256) {
        int rank = 0;
        for (int l = 0; l < neq; ++l) rank += (eqI[l] < eqI[j]) ? 1 : 0;
        if (rank < need) { candV[ngt + rank] = T; candI[ngt + rank] = eqI[j]; }
    }
    __syncthreads();
    // final ordering: (score desc, index asc)
    if (tid < KTOP) {
        const unsigned int u = candV[tid];
        const int idx = candI[tid];
        int rank = 0;
        for (int j = 0; j < KTOP; ++j)
            rank += (candV[j] > u || (candV[j] == u && candI[j] < idx)) ? 1 : 0;
        sel[b * KTOP + rank] = idx;
    }
}

// ---------------------------------------------------------------------------
// Kernel 3: gather selected rows + write indices (as float). Grid (40,16).
// ---------------------------------------------------------------------------
__global__ __launch_bounds__(192) void gather_kernel(const float* __restrict__ features,
                                                     const int* __restrict__ sel,
                                                     float* __restrict__ out_tok,
                                                     float* __restrict__ out_idx)
{
    const int i = blockIdx.x;   // 0..39
    const int b = blockIdx.y;   // 0..15
    const int idx = sel[b * KTOP + i];
    const float4* src = (const float4*)(features + ((size_t)b * S_ + idx) * D_);
    float4* dst = (float4*)(out_tok + ((size_t)b * KTOP + i) * D_);
    dst[threadIdx.x] = src[threadIdx.x];
    if (threadIdx.x == 0) out_idx[b * KTOP + i] = (float)idx;
}

// ---------------------------------------------------------------------------
extern "C" void kernel_launch(void* const* d_in, const int* in_sizes, int n_in,
                              void* d_out, int out_size, void* d_ws, size_t ws_size,
                              hipStream_t stream)
{
    const float* features = (const float*)d_in[0];
    const float* W1       = (const float*)d_in[1];
    const float* b1       = (const float*)d_in[2];
    const float* gamma    = (const float*)d_in[3];
    const float* beta     = (const float*)d_in[4];
    const float* W2       = (const float*)d_in[5];
    const float* b2       = (const float*)d_in[6];

    // ws layout
    unsigned short* bp = (unsigned short*)d_ws;            // 589824 elems (1.125 MB, hi/lo interleaved)
    float* scores      = (float*)(bp + (size_t)2 * D_ * H_);   // 256 KB
    int*   sel         = (int*)(scores + NTOK);            // 2.5 KB

    float* out        = (float*)d_out;
    float* out_tokens = out;                               // [16,40,768]
    float* out_idx    = out + (size_t)B_ * KTOP * D_;      // [16,40]

    pack_w1<<<dim3(NTILES, KCH), 64, 0, stream>>>(W1, bp);
    score_kernel<<<NTOK / 32, 256, 0, stream>>>(features, bp, b1, gamma, beta, W2, b2, scores);
    select_kernel<<<B_, 256, 0, stream>>>(scores, sel);
    gather_kernel<<<dim3(KTOP, B_), 192, 0, stream>>>(features, sel, out_tokens, out_idx);
}

// Round 6
// 429.537 us; speedup vs baseline: 1.1431x; 1.1431x over previous
//
#include <hip/hip_runtime.h>
#include <hip/hip_bf16.h>
#include <math.h>

#define B_   16
#define S_   4096
#define D_   768
#define H_   384
#define NTOK (B_ * S_)
#define KTOP 40
#define NTILES 24          // 384/16 n-tiles
#define KCH    24          // 768/32 k-chunks

typedef __attribute__((ext_vector_type(8))) short bf16x8;
typedef __attribute__((ext_vector_type(4))) float f32x4;

static __device__ __forceinline__ unsigned short f2bf(float x) {
    // HW RNE convert (same bits as the old software RNE path)
    __hip_bfloat16 h = __float2bfloat16(x);
    unsigned short r;
    __builtin_memcpy(&r, &h, sizeof(r));
    return r;
}
static __device__ __forceinline__ float bf2f(unsigned short h) {
    union { unsigned u; float f; } v; v.u = ((unsigned)h) << 16; return v.f;
}

// Raw workgroup barrier WITHOUT the vmcnt(0) drain __syncthreads() emits.
// lgkmcnt(0) orders LDS writes/reads across the barrier; global loads keep
// flying and are waited on by the compiler's per-consumer vmcnt.
// Memory-clobber asm on both sides pins LDS ops to their side of the barrier.
#define KBARRIER()                                                \
    do {                                                          \
        asm volatile("s_waitcnt lgkmcnt(0)" ::: "memory");        \
        __builtin_amdgcn_s_barrier();                             \
        asm volatile("" ::: "memory");                            \
    } while (0)

// ---------------------------------------------------------------------------
// Kernel 0: pack W1 (fp32 [768][384]) into MFMA B-fragment layout, bf16 hi/lo.
// Fragment element j of lane: B[k = chunk*32 + (lane>>4)*8 + j][n = ntile*16 + (lane&15)]
// packed[( (ntile*KCH + chunk)*64 + lane )*8 + j]   (v3 layout: lane stride
// 16B -> 1KB/wave coalesced loads; v5's per-lane-contiguous layout broke this)
// ---------------------------------------------------------------------------
__global__ __launch_bounds__(64) void pack_w1(const float* __restrict__ W1,
                                              unsigned short* __restrict__ bh,
                                              unsigned short* __restrict__ bl)
{
    const int nt   = blockIdx.x;        // 0..23
    const int ch   = blockIdx.y;        // 0..23
    const int lane = threadIdx.x;
    const int n    = nt * 16 + (lane & 15);
    const int k0   = ch * 32 + (lane >> 4) * 8;

    unsigned short h8[8], l8[8];
#pragma unroll
    for (int j = 0; j < 8; ++j) {
        const float v = W1[(size_t)(k0 + j) * H_ + n];
        const unsigned short h = f2bf(v);
        h8[j] = h;
        l8[j] = f2bf(v - bf2f(h));
    }
    const size_t base = ((size_t)(nt * KCH + ch) * 64 + lane) * 8;
#pragma unroll
    for (int j = 0; j < 8; ++j) { bh[base + j] = h8[j]; bl[base + j] = l8[j]; }
}

// ---------------------------------------------------------------------------
// Kernel 1: fused scores. v6 = v3 structure (best: 205us) with the barrier
// drain fixed:
//  - k-loop barriers are raw s_barrier + lgkmcnt(0) (NO vmcnt(0) drain).
//    v3's __syncthreads forced the A-prefetch to complete at barrier Y ->
//    every chunk exposed ~500-900cy of HBM latency to all 4 waves at once.
//  - A-prefetch moved to the top of the compute phase; it stays in flight
//    across the (non-draining) barriers until its convert next iteration.
//  - B layout reverted to v3 coalesced; HW f2bf kept (v5's one win).
// Block = 32 tokens x 384 cols (grid 2048), 4 waves; wave w owns n-tiles
// w*6..w*6+5 and 2 m-subtiles. acc 48 VGPR; launch_bounds(256,4) -> 4
// blocks/CU. Accumulation order identical -> scores bitwise identical.
// ---------------------------------------------------------------------------
__global__ __launch_bounds__(256, 4) void score_kernel(
    const float* __restrict__ features,
    const unsigned short* __restrict__ bh_g,
    const unsigned short* __restrict__ bl_g,
    const float* __restrict__ b1,
    const float* __restrict__ gamma,
    const float* __restrict__ beta,
    const float* __restrict__ W2,
    const float* __restrict__ b2,
    float* __restrict__ scores)
{
    __shared__ unsigned short Ah[32][40];   // pad 32->40 (16B-aligned rows)
    __shared__ unsigned short Al[32][40];
    __shared__ float red[4][32];
    __shared__ float mu_s[32];
    __shared__ float rs_s[32];

    const int tid  = threadIdx.x;
    const int lane = tid & 63;
    const int w    = tid >> 6;
    const int base = blockIdx.x * 32;
    const int cl   = lane & 15;
    const int p    = lane >> 4;

    f32x4 acc[2][6];
#pragma unroll
    for (int m = 0; m < 2; ++m)
#pragma unroll
        for (int t = 0; t < 6; ++t) acc[m][t] = (f32x4){0.f, 0.f, 0.f, 0.f};

    // staging map: thread covers one float4: row = tid>>3 (0..31), col4 = (tid&7)*4
    const int r0 = tid >> 3, c0 = (tid & 7) * 4;
    const float* arow = features + (size_t)(base + r0) * D_ + c0;

    float4 p0 = *(const float4*)(arow);     // A chunk 0

    for (int c = 0; c < KCH; ++c) {
        if (c) KBARRIER();                  // X: prev readers done (lgkm only)
        // convert + write staged chunk (p0 consumed here; compiler vmcnt-waits)
        {
            unsigned short h0 = f2bf(p0.x), h1 = f2bf(p0.y), h2 = f2bf(p0.z), h3 = f2bf(p0.w);
            Ah[r0][c0] = h0; Ah[r0][c0+1] = h1; Ah[r0][c0+2] = h2; Ah[r0][c0+3] = h3;
            Al[r0][c0]   = f2bf(p0.x - bf2f(h0));
            Al[r0][c0+1] = f2bf(p0.y - bf2f(h1));
            Al[r0][c0+2] = f2bf(p0.z - bf2f(h2));
            Al[r0][c0+3] = f2bf(p0.w - bf2f(h3));
        }
        KBARRIER();                         // Y: LDS chunk c ready (lgkm only)

        // prefetch next chunk's A NOW: in flight through the whole compute
        // phase and across the non-draining barriers (~900+cy cover)
        if (c + 1 < KCH) {
            p0 = *(const float4*)(arow + (c + 1) * 32);
        }

        // A fragments for the 2 m-subtiles
        bf16x8 ahf[2], alf[2];
#pragma unroll
        for (int m = 0; m < 2; ++m) {
            const int row = m * 16 + cl;
            ahf[m] = *(const bf16x8*)&Ah[row][p * 8];
            alf[m] = *(const bf16x8*)&Al[row][p * 8];
        }
        // B fragments per n-tile, MFMA immediately (limits B liveness)
#pragma unroll
        for (int t = 0; t < 6; ++t) {
            const size_t bb = ((size_t)((w * 6 + t) * KCH + c) * 64 + lane) * 8;
            const bf16x8 bhf = *(const bf16x8*)(bh_g + bb);
            const bf16x8 blf = *(const bf16x8*)(bl_g + bb);
#pragma unroll
            for (int m = 0; m < 2; ++m) {
                acc[m][t] = __builtin_amdgcn_mfma_f32_16x16x32_bf16(ahf[m], bhf, acc[m][t], 0, 0, 0);
                acc[m][t] = __builtin_amdgcn_mfma_f32_16x16x32_bf16(ahf[m], blf, acc[m][t], 0, 0, 0);
                acc[m][t] = __builtin_amdgcn_mfma_f32_16x16x32_bf16(alf[m], bhf, acc[m][t], 0, 0, 0);
            }
        }
    }

    // ---- epilogue: per-column constants ----
    float b1v[6], gv[6], bev[6], w2v[6];
#pragma unroll
    for (int t = 0; t < 6; ++t) {
        const int n = (w * 6 + t) * 16 + cl;
        b1v[t] = b1[n]; gv[t] = gamma[n]; bev[t] = beta[n]; w2v[t] = W2[n];
    }
    // h = acc + b1
#pragma unroll
    for (int m = 0; m < 2; ++m)
#pragma unroll
        for (int t = 0; t < 6; ++t)
#pragma unroll
            for (int r = 0; r < 4; ++r) acc[m][t][r] += b1v[t];

    // pass 1: row sums -> mean
#pragma unroll
    for (int m = 0; m < 2; ++m) {
        float sm[4] = {0.f, 0.f, 0.f, 0.f};
#pragma unroll
        for (int t = 0; t < 6; ++t)
#pragma unroll
            for (int r = 0; r < 4; ++r) sm[r] += acc[m][t][r];
#pragma unroll
        for (int r = 0; r < 4; ++r) {
#pragma unroll
            for (int off = 1; off <= 8; off <<= 1) sm[r] += __shfl_xor(sm[r], off, 64);
        }
        if (cl == 0) {
#pragma unroll
            for (int r = 0; r < 4; ++r) red[w][m * 16 + p * 4 + r] = sm[r];
        }
    }
    __syncthreads();
    if (tid < 32) mu_s[tid] = (red[0][tid] + red[1][tid] + red[2][tid] + red[3][tid]) * (1.0f / H_);
    __syncthreads();

    // pass 2: variance (two-pass, matches reference)
#pragma unroll
    for (int m = 0; m < 2; ++m) {
        float mur[4];
#pragma unroll
        for (int r = 0; r < 4; ++r) mur[r] = mu_s[m * 16 + p * 4 + r];
        float sm[4] = {0.f, 0.f, 0.f, 0.f};
#pragma unroll
        for (int t = 0; t < 6; ++t)
#pragma unroll
            for (int r = 0; r < 4; ++r) { const float d = acc[m][t][r] - mur[r]; sm[r] += d * d; }
#pragma unroll
        for (int r = 0; r < 4; ++r) {
#pragma unroll
            for (int off = 1; off <= 8; off <<= 1) sm[r] += __shfl_xor(sm[r], off, 64);
        }
        if (cl == 0) {
#pragma unroll
            for (int r = 0; r < 4; ++r) red[w][m * 16 + p * 4 + r] = sm[r];
        }
    }
    __syncthreads();
    if (tid < 32) rs_s[tid] = rsqrtf((red[0][tid] + red[1][tid] + red[2][tid] + red[3][tid]) * (1.0f / H_) + 1e-5f);
    __syncthreads();

    // pass 3: y = LN*gamma+beta, gelu, dot with W2
#pragma unroll
    for (int m = 0; m < 2; ++m) {
        float mur[4], rsr[4];
#pragma unroll
        for (int r = 0; r < 4; ++r) { mur[r] = mu_s[m * 16 + p * 4 + r]; rsr[r] = rs_s[m * 16 + p * 4 + r]; }
        float sm[4] = {0.f, 0.f, 0.f, 0.f};
#pragma unroll
        for (int t = 0; t < 6; ++t)
#pragma unroll
            for (int r = 0; r < 4; ++r) {
                const float y  = (acc[m][t][r] - mur[r]) * rsr[r] * gv[t] + bev[t];
                const float ge = 0.5f * y * (1.0f + erff(y * 0.70710678118654752f));
                sm[r] = fmaf(ge, w2v[t], sm[r]);
            }
#pragma unroll
        for (int r = 0; r < 4; ++r) {
#pragma unroll
            for (int off = 1; off <= 8; off <<= 1) sm[r] += __shfl_xor(sm[r], off, 64);
        }
        if (cl == 0) {
#pragma unroll
            for (int r = 0; r < 4; ++r) red[w][m * 16 + p * 4 + r] = sm[r];
        }
    }
    __syncthreads();
    if (tid < 32) {
        const float s = red[0][tid] + red[1][tid] + red[2][tid] + red[3][tid] + b2[0];
        scores[base + tid] = 1.0f / (1.0f + expf(-s));
    }
}

// ---------------------------------------------------------------------------
// Kernel 2: per-batch exact top-40 via byte-wise radix select on float bits
// (scores > 0 so uint order == float order). Ties -> lower index.
// Wave-parallel suffix-sum threshold scan (v4). Same semantics as serial.
// ---------------------------------------------------------------------------
__global__ __launch_bounds__(256) void select_kernel(const float* __restrict__ scores,
                                                     int* __restrict__ sel)
{
    __shared__ unsigned int bits_s[S_];     // 16 KB
    __shared__ unsigned int hist[256];
    __shared__ unsigned int suf[256];
    __shared__ unsigned int wtot[4];
    __shared__ int s_byte, s_rem;
    __shared__ unsigned int s_ngt, s_neq;
    __shared__ unsigned int candV[64];
    __shared__ int candI[64];
    __shared__ int eqI[256];

    const int b    = blockIdx.x;
    const int tid  = threadIdx.x;
    const int lane = tid & 63;
    const int w4   = tid >> 6;

    for (int i = tid; i < S_; i += 256)
        bits_s[i] = __float_as_uint(scores[b * S_ + i]);
    if (tid == 0) { s_rem = KTOP; s_ngt = 0u; s_neq = 0u; }

    unsigned int prefix = 0u, mask = 0u;
    for (int pb = 3; pb >= 0; --pb) {
        hist[tid] = 0u;
        __syncthreads();
        for (int i = tid; i < S_; i += 256) {
            const unsigned int u = bits_s[i];
            if ((u & mask) == prefix) atomicAdd(&hist[(u >> (8 * pb)) & 255u], 1u);
        }
        __syncthreads();
        // inclusive suffix sum over 256 bins: segment-local via shuffles
        {
            unsigned int v = hist[tid];
#pragma unroll
            for (int off = 1; off < 64; off <<= 1) {
                const unsigned int y = __shfl_down(v, off, 64);
                if (lane + off < 64) v += y;
            }
            if (lane == 0) wtot[w4] = v;   // segment totals
            __syncthreads();
            unsigned int add = 0u;
#pragma unroll
            for (int j = 0; j < 4; ++j) if (j > w4) add += wtot[j];
            v += add;
            suf[tid] = v;                  // suf[t] = #values with byte >= t (given prefix)
            __syncthreads();
            const int rem = s_rem;
            const unsigned int nxt = (tid < 255) ? suf[tid + 1] : 0u;
            if (suf[tid] >= (unsigned)rem && (tid == 255 || nxt < (unsigned)rem)) {
                s_byte = tid;
                s_rem  = rem - (int)nxt;   // subtract count strictly above byte
            }
        }
        __syncthreads();
        prefix |= ((unsigned int)s_byte) << (8 * pb);
        mask   |= 0xFFu << (8 * pb);
        __syncthreads();
    }
    const unsigned int T = prefix;
    const int need = s_rem;                 // 1..: #ties at T to keep

    for (int i = tid; i < S_; i += 256) {
        const unsigned int u = bits_s[i];
        if (u > T) {
            const unsigned int pos = atomicAdd(&s_ngt, 1u);
            candV[pos] = u; candI[pos] = i;          // n_gt <= 39 guaranteed
        } else if (u == T) {
            const unsigned int pos = atomicAdd(&s_neq, 1u);
            if (pos < 256u) eqI[pos] = i;
        }
    }
    __syncthreads();
    const int ngt = (int)s_ngt;
    const int neq = (int)(s_neq < 256u ? s_neq : 256u);
    // keep the `need` smallest indices among ties
    for (int j = tid; j < neq; j += 256) {
        int rank = 0;
        for (int l = 0; l < neq; ++l) rank += (eqI[l] < eqI[j]) ? 1 : 0;
        if (rank < need) { candV[ngt + rank] = T; candI[ngt + rank] = eqI[j]; }
    }
    __syncthreads();
    // final ordering: (score desc, index asc)
    if (tid < KTOP) {
        const unsigned int u = candV[tid];
        const int idx = candI[tid];
        int rank = 0;
        for (int j = 0; j < KTOP; ++j)
            rank += (candV[j] > u || (candV[j] == u && candI[j] < idx)) ? 1 : 0;
        sel[b * KTOP + rank] = idx;
    }
}

// ---------------------------------------------------------------------------
// Kernel 3: gather selected rows + write indices (as float). Grid (40,16).
// ---------------------------------------------------------------------------
__global__ __launch_bounds__(192) void gather_kernel(const float* __restrict__ features,
                                                     const int* __restrict__ sel,
                                                     float* __restrict__ out_tok,
                                                     float* __restrict__ out_idx)
{
    const int i = blockIdx.x;   // 0..39
    const int b = blockIdx.y;   // 0..15
    const int idx = sel[b * KTOP + i];
    const float4* src = (const float4*)(features + ((size_t)b * S_ + idx) * D_);
    float4* dst = (float4*)(out_tok + ((size_t)b * KTOP + i) * D_);
    dst[threadIdx.x] = src[threadIdx.x];
    if (threadIdx.x == 0) out_idx[b * KTOP + i] = (float)idx;
}

// ---------------------------------------------------------------------------
extern "C" void kernel_launch(void* const* d_in, const int* in_sizes, int n_in,
                              void* d_out, int out_size, void* d_ws, size_t ws_size,
                              hipStream_t stream)
{
    const float* features = (const float*)d_in[0];
    const float* W1       = (const float*)d_in[1];
    const float* b1       = (const float*)d_in[2];
    const float* gamma    = (const float*)d_in[3];
    const float* beta     = (const float*)d_in[4];
    const float* W2       = (const float*)d_in[5];
    const float* b2       = (const float*)d_in[6];

    // ws layout
    unsigned short* bh = (unsigned short*)d_ws;            // 294912 elems (576 KB)
    unsigned short* bl = bh + (size_t)D_ * H_;             // 576 KB
    float* scores      = (float*)(bl + (size_t)D_ * H_);   // 256 KB
    int*   sel         = (int*)(scores + NTOK);            // 2.5 KB

    float* out        = (float*)d_out;
    float* out_tokens = out;                               // [16,40,768]
    float* out_idx    = out + (size_t)B_ * KTOP * D_;      // [16,40]

    pack_w1<<<dim3(NTILES, KCH), 64, 0, stream>>>(W1, bh, bl);
    score_kernel<<<NTOK / 32, 256, 0, stream>>>(features, bh, bl, b1, gamma, beta, W2, b2, scores);
    select_kernel<<<B_, 256, 0, stream>>>(scores, sel);
    gather_kernel<<<dim3(KTOP, B_), 192, 0, stream>>>(features, sel, out_tokens, out_idx);
}